// Round 10
// baseline (124.494 us; speedup 1.0000x reference)
//
#include <hip/hip_runtime.h>
#include <hip/hip_bf16.h>

#define B_SZ 16384
#define SRCN 200
#define CAT  10
#define IN   2000
#define QCOL 500           // f32 cols per K-quarter
#define QPAD 512           // padded quarter cols
#define TQB  10240         // one quarter-table: 10 * 512 * 2B
#define NBLK 1024
#define EPSF 1e-10f

typedef _Float16 half2v __attribute__((ext_vector_type(2)));

#if __has_builtin(__builtin_amdgcn_fdot2)
__device__ __forceinline__ float fdot2(half2v a, half2v b, float c) {
    return __builtin_amdgcn_fdot2(a, b, c, false);
}
#else
__device__ __forceinline__ float fdot2(half2v a, half2v b, float c) {
    return c + (float)a[0] * (float)b[0] + (float)a[1] * (float)b[1];
}
#endif

__device__ __forceinline__ half2v pkrtz(float a, float b) {
#if __has_builtin(__builtin_amdgcn_cvt_pkrtz)
    union { __fp16 __attribute__((ext_vector_type(2))) i; half2v o; } v;
    v.i = __builtin_amdgcn_cvt_pkrtz(a, b);
    return v.o;
#else
    half2v r; r[0] = (_Float16)a; r[1] = (_Float16)b; return r;
#endif
}

__device__ __forceinline__ half2v as_h2(unsigned u) {
    union { unsigned u; half2v h; } v; v.u = u; return v.h;
}

__device__ __forceinline__ short f2h(float f) {
    union { _Float16 h; short s; } v; v.h = (_Float16)f; return v.s;
}

// ---------------------------------------------------------------------------
// Prep: f16 quarter-tables lp4/wy4 [q][cat][512] (zero past col 500),
// l1 = sum|W_yc| -> acc[2], zero acc[0..1].
// ---------------------------------------------------------------------------
__global__ void prep_kernel(const float* __restrict__ W_rec,
                            const float* __restrict__ b_rec,
                            const float* __restrict__ W_yc,
                            short* __restrict__ lp4,
                            short* __restrict__ wy4,
                            double* __restrict__ acc) {
    if (blockIdx.x == gridDim.x - 1) {
        float p = 0.f;
        for (int i = threadIdx.x; i < IN * CAT; i += blockDim.x) p += fabsf(W_yc[i]);
        __shared__ float red[4];
        for (int o = 32; o; o >>= 1) p += __shfl_down(p, o, 64);
        if ((threadIdx.x & 63) == 0) red[threadIdx.x >> 6] = p;
        __syncthreads();
        if (threadIdx.x == 0) {
            acc[0] = 0.0; acc[1] = 0.0;
            acc[2] = (double)(red[0] + red[1] + red[2] + red[3]);
        }
        return;
    }
    int idx = blockIdx.x * blockDim.x + threadIdx.x;   // 0 .. 20479
    int q   = idx / (CAT * QPAD);
    int rem = idx % (CAT * QPAD);
    int n   = rem >> 9;          // cat
    int kk  = rem & 511;
    short wv = 0, lv = 0;
    if (kk < QCOL) {
        int k = q * QCOL + kk;                 // global col, < 2000
        wv = f2h(W_yc[k * CAT + n]);
        int base = (k / CAT) * CAT;
        float lg[CAT];
        float m = -1e30f;
        #pragma unroll
        for (int i = 0; i < CAT; i++) {
            lg[i] = W_rec[n * IN + base + i] + b_rec[base + i];
            m = fmaxf(m, lg[i]);
        }
        float s = 0.f;
        #pragma unroll
        for (int i = 0; i < CAT; i++) s += expf(lg[i] - m);
        float myl = W_rec[n * IN + k] + b_rec[k];
        float pp = expf(myl - m) / s;
        lv = f2h(logf(EPSF + pp));
    }
    lp4[idx] = lv;
    wy4[idx] = wv;
}

// ---------------------------------------------------------------------------
// Main: persistent block = one K-quarter x 4 row-tiles (16 rows each).
// Tables (20 KB LDS) staged once. Per wave: 4 rows (g=l>>4), li=l&15 -> 4
// f32 cols per chunk. Register double-buffer at HALF-TILE granularity
// (4 chunks = 8 float4 loads = 2 KB/wave per slot): issue half h+2 right
// after compute(h) consumes its slot; sched_barrier(0) pins the loads
// against sinking. Steady state: 8-16 loads outstanding per wave, never
// drained -> load-queue duty cycle ~100% (the lever every prior round
// missed: compiler JIT scheduling gave ~25%).
// ---------------------------------------------------------------------------
__global__ __launch_bounds__(256, 4) void main_kernel(
        const float* __restrict__ x, const float* __restrict__ mask,
        const short* __restrict__ lp4, const short* __restrict__ wy4,
        float* __restrict__ part) {
    __shared__ __attribute__((aligned(16))) char lds[2 * TQB];   // 20 KB

    const int q = blockIdx.x & 3;
    {   // stage this quarter's tables: 2 x 640 uint4
        const uint4* s1 = (const uint4*)(lp4 + q * (CAT * QPAD));
        const uint4* s2 = (const uint4*)(wy4 + q * (CAT * QPAD));
        uint4* d1 = (uint4*)lds;
        uint4* d2 = (uint4*)(lds + TQB);
        #pragma unroll
        for (int i = 0; i < 3; ++i) {
            int j = i * 256 + threadIdx.x;
            if (j < 640) { d1[j] = s1[j]; d2[j] = s2[j]; }
        }
    }
    __syncthreads();

    const int l  = threadIdx.x & 63;
    const int w  = threadIdx.x >> 6;         // 0..3
    const int g  = l >> 4;                   // row-in-wave
    const int li = l & 15;                   // col group
    const int rt0 = blockIdx.x >> 2;         // 0..255
    const int col0 = q * QCOL + li * 4;

    // row for tile t (t = 0..3)
    auto rowOf = [&](int t) { return (rt0 + t * 256) * 16 + w * 4 + g; };

    // issue one half-tile (4 chunks) into a named slot
    auto issue = [&](float4* xv, float4* mv, int t, int hb) {
        const float* xr = x + (size_t)rowOf(t) * IN + col0;
        const float* mr = mask + (size_t)rowOf(t) * IN + col0;
        #pragma unroll
        for (int j = 0; j < 4; ++j) {
            const int cc = hb + j;
            int off = cc * 64;
            if (cc == 7) {                   // clamp (q=3, li>=13; table pad=0)
                const int base = col0 + 448;
                off -= (base > IN - 4) ? (base - (IN - 4)) : 0;
            }
            xv[j] = *(const float4*)(xr + off);
            mv[j] = *(const float4*)(mr + off);
        }
    };

    // consume one slot: 4 chunks of dot2 accumulation
    auto compute = [&](const float4* xv, const float4* mv, int hb,
                       float* pR, float* pW) {
        #pragma unroll
        for (int j = 0; j < 4; ++j) {
            const int cc = hb + j;
            const half2v ax0 = pkrtz(xv[j].x, xv[j].y);
            const half2v ax1 = pkrtz(xv[j].z, xv[j].w);
            const half2v am0 = pkrtz(xv[j].x * mv[j].x, xv[j].y * mv[j].y);
            const half2v am1 = pkrtz(xv[j].z * mv[j].z, xv[j].w * mv[j].w);
            const int tb = cc * 128 + li * 8;
            #pragma unroll
            for (int c = 0; c < CAT; ++c) {
                const uint2 lpv = *(const uint2*)(lds + c * 1024 + tb);
                const uint2 wyv = *(const uint2*)(lds + TQB + c * 1024 + tb);
                pR[c] = fdot2(am0, as_h2(lpv.x), pR[c]);
                pR[c] = fdot2(am1, as_h2(lpv.y), pR[c]);
                pW[c] = fdot2(ax0, as_h2(wyv.x), pW[c]);
                pW[c] = fdot2(ax1, as_h2(wyv.y), pW[c]);
            }
        }
    };

    auto reduceStore = [&](float* pR, float* pW, int t) {
        #pragma unroll
        for (int c = 0; c < CAT; ++c) {
            #pragma unroll
            for (int o = 1; o < 16; o <<= 1) {
                pR[c] += __shfl_xor(pR[c], o, 64);
                pW[c] += __shfl_xor(pW[c], o, 64);
            }
        }
        if (li == 0) {
            float* pp = part + ((size_t)rowOf(t) * 4 + q) * 20;
            #pragma unroll
            for (int c = 0; c < CAT; ++c) { pp[c] = pR[c]; pp[10 + c] = pW[c]; }
        }
    };

    float4 xA[4], mA[4], xB[4], mB[4];
    float pR[CAT], pW[CAT];

    // halves i = 0..7: tile = i>>1, chunk base = (i&1)*4. A holds even i.
    issue(xA, mA, 0, 0);
    issue(xB, mB, 0, 4);
    __builtin_amdgcn_sched_barrier(0);

    #pragma unroll
    for (int t = 0; t < 4; ++t) {
        #pragma unroll
        for (int c = 0; c < CAT; ++c) { pR[c] = 0.f; pW[c] = 0.f; }

        compute(xA, mA, 0, pR, pW);          // consumes slot A (half 2t)
        if (t < 3) {
            issue(xA, mA, t + 1, 0);         // half 2t+2 -> slot A
            __builtin_amdgcn_sched_barrier(0);
        }
        compute(xB, mB, 4, pR, pW);          // consumes slot B (half 2t+1)
        if (t < 3) {
            issue(xB, mB, t + 1, 4);         // half 2t+3 -> slot B
            __builtin_amdgcn_sched_barrier(0);
        }
        reduceStore(pR, pW, t);              // shuffles run while loads fly
    }
}

// ---------------------------------------------------------------------------
// Combine: per row, sum 4 quarter-partials, softmax, write y, loss partials.
// ---------------------------------------------------------------------------
__global__ void combine_kernel(const float* __restrict__ part,
                               const float* __restrict__ y_target,
                               const float* __restrict__ b_yc,
                               float* __restrict__ out,
                               double* __restrict__ acc) {
    const int row = blockIdx.x * 256 + threadIdx.x;
    const float* pp = part + (size_t)row * 80;
    float pR[CAT], pW[CAT];
    #pragma unroll
    for (int c = 0; c < CAT; ++c) {
        pR[c] = pp[c] + pp[20 + c] + pp[40 + c] + pp[60 + c];
        pW[c] = pp[10 + c] + pp[30 + c] + pp[50 + c] + pp[70 + c] + b_yc[c];
    }
    float mx = -1e30f;
    #pragma unroll
    for (int c = 0; c < CAT; ++c) mx = fmaxf(mx, pW[c]);
    float y[CAT], s = 0.f;
    #pragma unroll
    for (int c = 0; c < CAT; ++c) { y[c] = __expf(pW[c] - mx); s += y[c]; }
    const float is = 1.f / s;
    float cls = 0.f, kl = 0.f;
    float* op = out + (size_t)row * CAT;
    #pragma unroll
    for (int c = 0; c < CAT; ++c) {
        y[c] *= is;
        op[c] = y[c];
        cls += y[c] * (-pR[c] * (1.f / IN));
        const float yt = y_target[(size_t)row * CAT + c];
        kl += y[c] * (__logf(EPSF + y[c]) - __logf(EPSF + yt));
    }
    #pragma unroll
    for (int o = 32; o; o >>= 1) {
        cls += __shfl_down(cls, o, 64);
        kl  += __shfl_down(kl, o, 64);
    }
    __shared__ float rc[4], rk[4];
    if ((threadIdx.x & 63) == 0) {
        rc[threadIdx.x >> 6] = cls; rk[threadIdx.x >> 6] = kl;
    }
    __syncthreads();
    if (threadIdx.x == 0) {
        atomicAdd(&acc[0], (double)(rc[0] + rc[1] + rc[2] + rc[3]));
        atomicAdd(&acc[1], (double)(rk[0] + rk[1] + rk[2] + rk[3]));
    }
}

__global__ void final_kernel(const double* __restrict__ acc,
                             float* __restrict__ out) {
    if (threadIdx.x == 0) {
        double loss = acc[0] / (double)B_SZ
                    + 1e-4 * (acc[1] / (double)B_SZ)
                    + (0.005 / (double)SRCN / (double)CAT / (double)CAT) * acc[2];
        out[(size_t)B_SZ * CAT] = (float)loss;
    }
}

extern "C" void kernel_launch(void* const* d_in, const int* in_sizes, int n_in,
                              void* d_out, int out_size, void* d_ws, size_t ws_size,
                              hipStream_t stream) {
    const float* x        = (const float*)d_in[0];
    const float* mask     = (const float*)d_in[1];
    const float* y_target = (const float*)d_in[2];
    const float* W_rec    = (const float*)d_in[3];
    const float* b_rec    = (const float*)d_in[4];
    const float* W_yc     = (const float*)d_in[5];
    const float* b_yc     = (const float*)d_in[6];
    float* out  = (float*)d_out;
    double* acc = (double*)d_ws;
    short* lp4  = (short*)((char*)d_ws + 256);            // 4*10*512 f16
    short* wy4  = lp4 + 4 * CAT * QPAD;
    float* part = (float*)((char*)d_ws + 256 + 2 * 40960); // 16384*80 f32

    // 80 table blocks (20480 entries) + 1 l1/zero block
    prep_kernel<<<81, 256, 0, stream>>>(W_rec, b_rec, W_yc, lp4, wy4, acc);
    // 1024 persistent blocks (4 blocks/CU), each: 1 quarter x 4 row-tiles
    main_kernel<<<NBLK, 256, 0, stream>>>(x, mask, lp4, wy4, part);
    combine_kernel<<<64, 256, 0, stream>>>(part, y_target, b_yc, out, acc);
    final_kernel<<<1, 64, 0, stream>>>(acc, out);
}

// Round 11
// 71.934 us; speedup vs baseline: 1.7307x; 1.7307x over previous
//
#include <hip/hip_runtime.h>
#include <hip/hip_bf16.h>

#define B_SZ 16384
#define SRCN 200
#define CAT  10
#define IN   2000
#define QCOL 500           // f32 cols per K-quarter
#define QPAD 512           // padded quarter cols
#define TQB  10240         // one quarter-table: 10 * 512 * 2B
#define EPSF 1e-10f

typedef float f32x4 __attribute__((ext_vector_type(4)));
typedef _Float16 half2v __attribute__((ext_vector_type(2)));

#if __has_builtin(__builtin_amdgcn_fdot2)
__device__ __forceinline__ float fdot2(half2v a, half2v b, float c) {
    return __builtin_amdgcn_fdot2(a, b, c, false);
}
#else
__device__ __forceinline__ float fdot2(half2v a, half2v b, float c) {
    return c + (float)a[0] * (float)b[0] + (float)a[1] * (float)b[1];
}
#endif

__device__ __forceinline__ half2v pkrtz(float a, float b) {
#if __has_builtin(__builtin_amdgcn_cvt_pkrtz)
    union { __fp16 __attribute__((ext_vector_type(2))) i; half2v o; } v;
    v.i = __builtin_amdgcn_cvt_pkrtz(a, b);
    return v.o;
#else
    half2v r; r[0] = (_Float16)a; r[1] = (_Float16)b; return r;
#endif
}

__device__ __forceinline__ half2v as_h2(unsigned u) {
    union { unsigned u; half2v h; } v; v.u = u; return v.h;
}

__device__ __forceinline__ short f2h(float f) {
    union { _Float16 h; short s; } v; v.h = (_Float16)f; return v.s;
}

// ---------------------------------------------------------------------------
// Prep: f16 quarter-tables lp4/wy4 [q][cat][512] (zero past col 500),
// l1 = sum|W_yc| -> acc[2], zero acc[0..1].
// ---------------------------------------------------------------------------
__global__ void prep_kernel(const float* __restrict__ W_rec,
                            const float* __restrict__ b_rec,
                            const float* __restrict__ W_yc,
                            short* __restrict__ lp4,
                            short* __restrict__ wy4,
                            double* __restrict__ acc) {
    if (blockIdx.x == gridDim.x - 1) {
        float p = 0.f;
        for (int i = threadIdx.x; i < IN * CAT; i += blockDim.x) p += fabsf(W_yc[i]);
        __shared__ float red[4];
        for (int o = 32; o; o >>= 1) p += __shfl_down(p, o, 64);
        if ((threadIdx.x & 63) == 0) red[threadIdx.x >> 6] = p;
        __syncthreads();
        if (threadIdx.x == 0) {
            acc[0] = 0.0; acc[1] = 0.0;
            acc[2] = (double)(red[0] + red[1] + red[2] + red[3]);
        }
        return;
    }
    int idx = blockIdx.x * blockDim.x + threadIdx.x;   // 0 .. 20479
    int q   = idx / (CAT * QPAD);
    int rem = idx % (CAT * QPAD);
    int n   = rem >> 9;          // cat
    int kk  = rem & 511;
    short wv = 0, lv = 0;
    if (kk < QCOL) {
        int k = q * QCOL + kk;                 // global col, < 2000
        wv = f2h(W_yc[k * CAT + n]);
        int base = (k / CAT) * CAT;
        float lg[CAT];
        float m = -1e30f;
        #pragma unroll
        for (int i = 0; i < CAT; i++) {
            lg[i] = W_rec[n * IN + base + i] + b_rec[base + i];
            m = fmaxf(m, lg[i]);
        }
        float s = 0.f;
        #pragma unroll
        for (int i = 0; i < CAT; i++) s += expf(lg[i] - m);
        float myl = W_rec[n * IN + k] + b_rec[k];
        float pp = expf(myl - m) / s;
        lv = f2h(logf(EPSF + pp));
    }
    lp4[idx] = lv;
    wy4[idx] = wv;
}

// ---------------------------------------------------------------------------
// Main: block = 16 rows x one K-quarter; 4 waves, wave owns 4 rows
// (g=l>>4 picks the row, li=l&15 picks 4 cols/chunk). The 16 float4 loads
// (8 x + 8 mask, 16 KB/wave) are INLINE-ASM global_load_dwordx4, issued
// consecutively up front (volatile => compiler cannot sink them); each
// chunk's compute is gated by an inline-asm counted s_waitcnt vmcnt(N)
// whose "+v" operands tie the loaded values through the wait (data-dep
// ordering). Queue depth stays 2..16 for the whole compute phase.
// Tables f16 in 20 KB LDS (lgkmcnt domain, compiler-managed).
// ---------------------------------------------------------------------------
__global__ __launch_bounds__(256, 4) void main_kernel(
        const float* __restrict__ x, const float* __restrict__ mask,
        const short* __restrict__ lp4, const short* __restrict__ wy4,
        float* __restrict__ part) {
    __shared__ __attribute__((aligned(16))) char lds[2 * TQB];   // 20 KB

    const int q = blockIdx.x & 3;
    {   // stage this quarter's tables: 2 x 640 uint4
        const uint4* s1 = (const uint4*)(lp4 + q * (CAT * QPAD));
        const uint4* s2 = (const uint4*)(wy4 + q * (CAT * QPAD));
        uint4* d1 = (uint4*)lds;
        uint4* d2 = (uint4*)(lds + TQB);
        #pragma unroll
        for (int i = 0; i < 3; ++i) {
            int j = i * 256 + threadIdx.x;
            if (j < 640) { d1[j] = s1[j]; d2[j] = s2[j]; }
        }
    }
    __syncthreads();

    const int l  = threadIdx.x & 63;
    const int w  = threadIdx.x >> 6;         // 0..3
    const int g  = l >> 4;                   // row-in-wave
    const int li = l & 15;                   // col group
    const int row = (blockIdx.x >> 2) * 16 + w * 4 + g;

    const int col0 = q * QCOL + li * 4;      // q*500 f32 = 2000 B, 16B-aligned
    const float* xr = x + (size_t)row * IN + col0;
    const float* mr = mask + (size_t)row * IN + col0;
    // chunk 7 clamp (only q=3, li>=13 overruns; table cols >= 500 are zero)
    const int b7  = col0 + 448;
    const int adj = (b7 > IN - 4) ? (b7 - (IN - 4)) : 0;
    const float* xr7 = xr + 448 - adj;
    const float* mr7 = mr + 448 - adj;

    // ---- issue ALL 16 loads up front, interleaved x/m per chunk
    f32x4 X0, X1, X2, X3, X4, X5, X6, X7;
    f32x4 M0, M1, M2, M3, M4, M5, M6, M7;
    asm volatile("global_load_dwordx4 %0, %1, off"             : "=&v"(X0) : "v"(xr)  : "memory");
    asm volatile("global_load_dwordx4 %0, %1, off"             : "=&v"(M0) : "v"(mr)  : "memory");
    asm volatile("global_load_dwordx4 %0, %1, off offset:256"  : "=&v"(X1) : "v"(xr)  : "memory");
    asm volatile("global_load_dwordx4 %0, %1, off offset:256"  : "=&v"(M1) : "v"(mr)  : "memory");
    asm volatile("global_load_dwordx4 %0, %1, off offset:512"  : "=&v"(X2) : "v"(xr)  : "memory");
    asm volatile("global_load_dwordx4 %0, %1, off offset:512"  : "=&v"(M2) : "v"(mr)  : "memory");
    asm volatile("global_load_dwordx4 %0, %1, off offset:768"  : "=&v"(X3) : "v"(xr)  : "memory");
    asm volatile("global_load_dwordx4 %0, %1, off offset:768"  : "=&v"(M3) : "v"(mr)  : "memory");
    asm volatile("global_load_dwordx4 %0, %1, off offset:1024" : "=&v"(X4) : "v"(xr)  : "memory");
    asm volatile("global_load_dwordx4 %0, %1, off offset:1024" : "=&v"(M4) : "v"(mr)  : "memory");
    asm volatile("global_load_dwordx4 %0, %1, off offset:1280" : "=&v"(X5) : "v"(xr)  : "memory");
    asm volatile("global_load_dwordx4 %0, %1, off offset:1280" : "=&v"(M5) : "v"(mr)  : "memory");
    asm volatile("global_load_dwordx4 %0, %1, off offset:1536" : "=&v"(X6) : "v"(xr)  : "memory");
    asm volatile("global_load_dwordx4 %0, %1, off offset:1536" : "=&v"(M6) : "v"(mr)  : "memory");
    asm volatile("global_load_dwordx4 %0, %1, off"             : "=&v"(X7) : "v"(xr7) : "memory");
    asm volatile("global_load_dwordx4 %0, %1, off"             : "=&v"(M7) : "v"(mr7) : "memory");

    float pR[CAT], pW[CAT];
    #pragma unroll
    for (int c = 0; c < CAT; ++c) { pR[c] = 0.f; pW[c] = 0.f; }

    // consume one chunk (values already waited-on)
    auto dochunk = [&](f32x4 xv, f32x4 mv, int cc) {
        const half2v ax0 = pkrtz(xv[0], xv[1]);
        const half2v ax1 = pkrtz(xv[2], xv[3]);
        const half2v am0 = pkrtz(xv[0] * mv[0], xv[1] * mv[1]);
        const half2v am1 = pkrtz(xv[2] * mv[2], xv[3] * mv[3]);
        const int tb = cc * 128 + li * 8;    // byte offset in [512]-col cat row
        #pragma unroll
        for (int c = 0; c < CAT; ++c) {
            const uint2 lpv = *(const uint2*)(lds + c * 1024 + tb);
            const uint2 wyv = *(const uint2*)(lds + TQB + c * 1024 + tb);
            pR[c] = fdot2(am0, as_h2(lpv.x), pR[c]);
            pR[c] = fdot2(am1, as_h2(lpv.y), pR[c]);
            pW[c] = fdot2(ax0, as_h2(wyv.x), pW[c]);
            pW[c] = fdot2(ax1, as_h2(wyv.y), pW[c]);
        }
    };

    asm volatile("s_waitcnt vmcnt(14)" : "+v"(X0), "+v"(M0)); dochunk(X0, M0, 0);
    asm volatile("s_waitcnt vmcnt(12)" : "+v"(X1), "+v"(M1)); dochunk(X1, M1, 1);
    asm volatile("s_waitcnt vmcnt(10)" : "+v"(X2), "+v"(M2)); dochunk(X2, M2, 2);
    asm volatile("s_waitcnt vmcnt(8)"  : "+v"(X3), "+v"(M3)); dochunk(X3, M3, 3);
    asm volatile("s_waitcnt vmcnt(6)"  : "+v"(X4), "+v"(M4)); dochunk(X4, M4, 4);
    asm volatile("s_waitcnt vmcnt(4)"  : "+v"(X5), "+v"(M5)); dochunk(X5, M5, 5);
    asm volatile("s_waitcnt vmcnt(2)"  : "+v"(X6), "+v"(M6)); dochunk(X6, M6, 6);
    asm volatile("s_waitcnt vmcnt(0)"  : "+v"(X7), "+v"(M7)); dochunk(X7, M7, 7);

    // ---- 4-step butterfly within each 16-lane group (one row per group)
    #pragma unroll
    for (int c = 0; c < CAT; ++c) {
        #pragma unroll
        for (int o = 1; o < 16; o <<= 1) {
            pR[c] += __shfl_xor(pR[c], o, 64);
            pW[c] += __shfl_xor(pW[c], o, 64);
        }
    }
    if (li == 0) {
        float* pp = part + ((size_t)row * 4 + q) * 20;
        #pragma unroll
        for (int c = 0; c < CAT; ++c) { pp[c] = pR[c]; pp[10 + c] = pW[c]; }
    }
}

// ---------------------------------------------------------------------------
// Combine: per row, sum 4 quarter-partials, softmax, write y, loss partials.
// ---------------------------------------------------------------------------
__global__ void combine_kernel(const float* __restrict__ part,
                               const float* __restrict__ y_target,
                               const float* __restrict__ b_yc,
                               float* __restrict__ out,
                               double* __restrict__ acc) {
    const int row = blockIdx.x * 256 + threadIdx.x;
    const float* pp = part + (size_t)row * 80;
    float pR[CAT], pW[CAT];
    #pragma unroll
    for (int c = 0; c < CAT; ++c) {
        pR[c] = pp[c] + pp[20 + c] + pp[40 + c] + pp[60 + c];
        pW[c] = pp[10 + c] + pp[30 + c] + pp[50 + c] + pp[70 + c] + b_yc[c];
    }
    float mx = -1e30f;
    #pragma unroll
    for (int c = 0; c < CAT; ++c) mx = fmaxf(mx, pW[c]);
    float y[CAT], s = 0.f;
    #pragma unroll
    for (int c = 0; c < CAT; ++c) { y[c] = __expf(pW[c] - mx); s += y[c]; }
    const float is = 1.f / s;
    float cls = 0.f, kl = 0.f;
    float* op = out + (size_t)row * CAT;
    #pragma unroll
    for (int c = 0; c < CAT; ++c) {
        y[c] *= is;
        op[c] = y[c];
        cls += y[c] * (-pR[c] * (1.f / IN));
        const float yt = y_target[(size_t)row * CAT + c];
        kl += y[c] * (__logf(EPSF + y[c]) - __logf(EPSF + yt));
    }
    #pragma unroll
    for (int o = 32; o; o >>= 1) {
        cls += __shfl_down(cls, o, 64);
        kl  += __shfl_down(kl, o, 64);
    }
    __shared__ float rc[4], rk[4];
    if ((threadIdx.x & 63) == 0) {
        rc[threadIdx.x >> 6] = cls; rk[threadIdx.x >> 6] = kl;
    }
    __syncthreads();
    if (threadIdx.x == 0) {
        atomicAdd(&acc[0], (double)(rc[0] + rc[1] + rc[2] + rc[3]));
        atomicAdd(&acc[1], (double)(rk[0] + rk[1] + rk[2] + rk[3]));
    }
}

__global__ void final_kernel(const double* __restrict__ acc,
                             float* __restrict__ out) {
    if (threadIdx.x == 0) {
        double loss = acc[0] / (double)B_SZ
                    + 1e-4 * (acc[1] / (double)B_SZ)
                    + (0.005 / (double)SRCN / (double)CAT / (double)CAT) * acc[2];
        out[(size_t)B_SZ * CAT] = (float)loss;
    }
}

extern "C" void kernel_launch(void* const* d_in, const int* in_sizes, int n_in,
                              void* d_out, int out_size, void* d_ws, size_t ws_size,
                              hipStream_t stream) {
    const float* x        = (const float*)d_in[0];
    const float* mask     = (const float*)d_in[1];
    const float* y_target = (const float*)d_in[2];
    const float* W_rec    = (const float*)d_in[3];
    const float* b_rec    = (const float*)d_in[4];
    const float* W_yc     = (const float*)d_in[5];
    const float* b_yc     = (const float*)d_in[6];
    float* out  = (float*)d_out;
    double* acc = (double*)d_ws;
    short* lp4  = (short*)((char*)d_ws + 256);            // 4*10*512 f16
    short* wy4  = lp4 + 4 * CAT * QPAD;
    float* part = (float*)((char*)d_ws + 256 + 2 * 40960); // 16384*80 f32

    // 80 table blocks (20480 entries) + 1 l1/zero block
    prep_kernel<<<81, 256, 0, stream>>>(W_rec, b_rec, W_yc, lp4, wy4, acc);
    // 1024 row-tiles of 16 rows x 4 K-quarters = 4096 blocks
    main_kernel<<<4096, 256, 0, stream>>>(x, mask, lp4, wy4, part);
    combine_kernel<<<64, 256, 0, stream>>>(part, y_target, b_yc, out, acc);
    final_kernel<<<1, 64, 0, stream>>>(acc, out);
}